// Round 22
// baseline (164.207 us; speedup 1.0000x reference)
//
#include <hip/hip_runtime.h>

#define C_DIM 768
#define NHEADS 12
#define HDIM 64
#define BATCH 8
#define SEQ 1024
#define SCALE2 0.1803368801f    // 64^-0.5 * log2(e): softmax in exp2 domain
#define DEFER_THR 11.5415603f   // 8 * log2(e)
#define LOG2E 1.44269504089f
#define TBL 3969                // 63*63 per head
#define BTSL2 2457              // 39*63 per-block bias slice (256 q-rows)

typedef float f32x4 __attribute__((ext_vector_type(4)));
typedef short s16x4 __attribute__((ext_vector_type(4)));
typedef short s16x8 __attribute__((ext_vector_type(8)));
typedef unsigned int u32x2 __attribute__((ext_vector_type(2)));

// single-op bf16 convert (RNE) — no builtin on gfx950
__device__ inline unsigned short f2bf(float f) {
    unsigned r;
    asm("v_cvt_pk_bf16_f32 %0, %1, %2" : "=v"(r) : "v"(f), "v"(f));
    return (unsigned short)r;
}
// packed pair: low16 = bf16(lo), high16 = bf16(hi)
__device__ inline unsigned cvtpk(float lo, float hi) {
    unsigned r;
    asm("v_cvt_pk_bf16_f32 %0, %1, %2" : "=v"(r) : "v"(lo), "v"(hi));
    return r;
}

#define GLOAD_LDS16(gsrc, ldst)                                                   \
    __builtin_amdgcn_global_load_lds(                                             \
        (const __attribute__((address_space(1))) unsigned int*)(gsrc),            \
        (__attribute__((address_space(3))) unsigned int*)(ldst), 16, 0, 0)

// ---------------- ws layout (bytes) ----------------
// q_bf    [B][H][N][D] bf16   off 0          12582912
// k_bf    [B][H][N][D] bf16   off 12582912   12582912
// vT_bf   [B][H][D][N] bf16   off 25165824   12582912
// abuf    [B][N][C]    bf16   off 37748736   12582912
// btab    [H][63][63]  f32    off 50331648   190512   (pre-scaled by log2e)
// x_bf    [8192][768]  bf16   off 50522160   12582912
// qkvw_bf [2304][768]  bf16   off 63105072   3538944
// projw_bf[768][768]   bf16   off 66644016   1179648

// ===== merged prep kernel: f32->bf16 casts (x|qkv_w|proj_w) + rpb table =====
#define XU   786432            // x units (8 f32 each)
#define QWU  221184            // qkv_w units
#define PWU  73728             // proj_w units
#define CVTB 4224              // cast blocks: (XU+QWU+PWU)/256
__global__ __launch_bounds__(256)
void prep_kernel(const float* __restrict__ x, unsigned short* __restrict__ xo,
                 const float* __restrict__ qw, unsigned short* __restrict__ qwo,
                 const float* __restrict__ pw, unsigned short* __restrict__ pwo,
                 const float* __restrict__ w1, const float* __restrict__ b1,
                 const float* __restrict__ w2, const float* __restrict__ b2,
                 float* __restrict__ btab)
{
    if (blockIdx.x >= CVTB) {   // rpb table portion (pre-scaled by log2e)
        int t = (blockIdx.x - CVTB) * 256 + threadIdx.x;
        if (t >= TBL) return;
        float dy = (float)(t / 63 - 31);
        float dx = (float)(t % 63 - 31);
        float acc[NHEADS];
#pragma unroll
        for (int h = 0; h < NHEADS; ++h) acc[h] = b2[h];
        for (int j = 0; j < 64; ++j) {
            float hj = fmaf(w1[j * 2], dx, fmaf(w1[j * 2 + 1], dy, b1[j]));
            hj = fmaxf(hj, 0.f);
#pragma unroll
            for (int h = 0; h < NHEADS; ++h) acc[h] = fmaf(w2[h * 64 + j], hj, acc[h]);
        }
#pragma unroll
        for (int h = 0; h < NHEADS; ++h) btab[h * TBL + t] = acc[h] * LOG2E;
        return;
    }
    int i = blockIdx.x * 256 + threadIdx.x;
    const float* in; unsigned short* out;
    if (i < XU)                  { in = x;  out = xo; }
    else if (i < XU + QWU)       { in = qw; out = qwo; i -= XU; }
    else                         { in = pw; out = pwo; i -= XU + QWU; }
    const float4* p = (const float4*)in + (size_t)i * 2;
    float4 a = p[0], b = p[1];
    s16x8 v;
    v[0] = (short)f2bf(a.x); v[1] = (short)f2bf(a.y);
    v[2] = (short)f2bf(a.z); v[3] = (short)f2bf(a.w);
    v[4] = (short)f2bf(b.x); v[5] = (short)f2bf(b.y);
    v[6] = (short)f2bf(b.z); v[7] = (short)f2bf(b.w);
    *((s16x8*)out + i) = v;
}

// ============ Phase-interleaved MFMA GEMM — 128x128, 4 waves, BK=64 ============
// (round-19 configuration: session best across 9 structural variants.)

#define MFMA_SWAP(aa, bb)                                          \
    _Pragma("unroll") for (int i_ = 0; i_ < 4; ++i_)               \
    _Pragma("unroll") for (int j_ = 0; j_ < 4; ++j_)               \
        acc[i_][j_] = __builtin_amdgcn_mfma_f32_16x16x32_bf16(     \
            bb[j_], aa[i_], acc[i_][j_], 0, 0, 0);

#define MFMA_NORM(aa, bb)                                          \
    _Pragma("unroll") for (int i_ = 0; i_ < 4; ++i_)               \
    _Pragma("unroll") for (int j_ = 0; j_ < 4; ++j_)               \
        acc[i_][j_] = __builtin_amdgcn_mfma_f32_16x16x32_bf16(     \
            aa[i_], bb[j_], acc[i_][j_], 0, 0, 0);

// stage half of a K-tile: wave w covers A rows w*32+half*16+{0..15} (2 calls)
// and B rows likewise (2 calls) -> 4 loads per wave per half
#define STG_HALF(buf, kt, half)                                                    \
    GLOAD_LDS16(Ab + ((size_t)(m0 + w * 32 + (half) * 16 + srow8) * 768 +          \
                (kt) * 64) * 2 + sch8 * 16, &Al[buf][w * 32 + (half) * 16][0]);    \
    GLOAD_LDS16(Ab + ((size_t)(m0 + w * 32 + (half) * 16 + 8 + srow8) * 768 +      \
                (kt) * 64) * 2 + sch8 * 16, &Al[buf][w * 32 + (half) * 16 + 8][0]);\
    GLOAD_LDS16(Wb + ((size_t)(n0 + w * 32 + (half) * 16 + srow8) * 768 +          \
                (kt) * 64) * 2 + sch8 * 16, &Bl[buf][w * 32 + (half) * 16][0]);    \
    GLOAD_LDS16(Wb + ((size_t)(n0 + w * 32 + (half) * 16 + 8 + srow8) * 768 +      \
                (kt) * 64) * 2 + sch8 * 16, &Bl[buf][w * 32 + (half) * 16 + 8][0]);

// phase fragment reads: logical chunk s*4+lhi at physical (c ^ (row&7))
#define PHASE_READS(cur, s, ar, br)                                                \
    _Pragma("unroll") for (int i_ = 0; i_ < 4; ++i_) {                             \
        ar[i_] = *(const s16x8*)((const char*)&Al[cur][wr * 64 + i_ * 16 + l15][0] \
                 + ((((s) * 4 + lhi) ^ (l15 & 7)) * 16));                          \
        br[i_] = *(const s16x8*)((const char*)&Bl[cur][wc * 64 + i_ * 16 + l15][0] \
                 + ((((s) * 4 + lhi) ^ (l15 & 7)) * 16));                          \
    }

__global__ __launch_bounds__(256)
void gemm_qkv_mfma(const unsigned short* __restrict__ A,
                   const unsigned short* __restrict__ W,
                   unsigned short* __restrict__ qo, unsigned short* __restrict__ ko,
                   unsigned short* __restrict__ vto)
{
    __shared__ unsigned short Al[2][128][64];   // 32 KB
    __shared__ unsigned short Bl[2][128][64];   // 32 KB

    // bijective XCD swizzle: 1152 = 8 x 144
    const int b0 = blockIdx.x;
    const int sw = (b0 & 7) * 144 + (b0 >> 3);
    const int bx = sw % 18, by = sw / 18;
    const int m0 = by * 128;
    const int n0 = bx * 128;
    const int lane = threadIdx.x & 63, w = threadIdx.x >> 6;   // w 0..3
    const int wr = w >> 1, wc = w & 1;                          // 2m x 2n
    const int l15 = lane & 15, lhi = lane >> 4;

    const int which = n0 / 768;              // 0=q 1=k 2=v (block-uniform)
    const int ncol0 = n0 - which * 768;

    const int srow8 = lane >> 3;             // 0..7 within 8-row group
    const int sch8  = (lane & 7) ^ srow8;    // pre-swizzled global chunk

    f32x4 acc[4][4];
#pragma unroll
    for (int i = 0; i < 4; ++i)
#pragma unroll
        for (int j = 0; j < 4; ++j)
            acc[i][j] = (f32x4){0.f, 0.f, 0.f, 0.f};

    const char* Ab = (const char*)A;
    const char* Wb = (const char*)W;

    STG_HALF(0, 0, 0)
    STG_HALF(0, 0, 1)

    for (int kt = 0; kt < 12; ++kt) {
        const int cur = kt & 1;
        if (kt + 1 < 12) {
            STG_HALF(cur ^ 1, kt + 1, 0)                       // batch1(kt+1)
            asm volatile("s_waitcnt vmcnt(4)" ::: "memory");   // tile kt landed
        } else {
            asm volatile("s_waitcnt vmcnt(0)" ::: "memory");
        }
        __builtin_amdgcn_s_barrier();

        {   // phase 1: k-lo (compiler fine-schedules ds_read -> MFMA)
            s16x8 ar[4], br[4];
            PHASE_READS(cur, 0, ar, br)
            if (kt + 1 < 12) { STG_HALF(cur ^ 1, kt + 1, 1) }  // batch2(kt+1)
            __builtin_amdgcn_s_setprio(1);
            if (which < 2) { MFMA_SWAP(ar, br) } else { MFMA_NORM(ar, br) }
            __builtin_amdgcn_s_setprio(0);
        }
        __builtin_amdgcn_s_barrier();

        {   // phase 2: k-hi
            s16x8 ar[4], br[4];
            PHASE_READS(cur, 1, ar, br)
            __builtin_amdgcn_s_setprio(1);
            if (which < 2) { MFMA_SWAP(ar, br) } else { MFMA_NORM(ar, br) }
            __builtin_amdgcn_s_setprio(0);
        }
        __builtin_amdgcn_s_barrier();   // all reads of buf[cur] done -> reusable
    }

    const int h = (ncol0 >> 6) + wc;         // 64-col wave block = one head's d-range
    if (which < 2) {
        // swapped: D[n][m], m on l15 axis -> contiguous d-stores
        unsigned short* dst0 = (which == 0) ? qo : ko;
#pragma unroll
        for (int i = 0; i < 4; ++i) {
            int mm = m0 + wr * 64 + i * 16 + l15;
            int b_ = mm >> 10, nn = mm & 1023;
            unsigned short* rowp = dst0 + (((size_t)(b_ * NHEADS + h) * SEQ + nn) << 6);
#pragma unroll
            for (int j = 0; j < 4; ++j) {
                s16x4 v;
#pragma unroll
                for (int r = 0; r < 4; ++r) v[r] = (short)f2bf(acc[i][j][r]);
                *(s16x4*)(rowp + j * 16 + lhi * 4) = v;
            }
        }
    } else {
        // normal: D[m][n]; m contiguous over reg -> vT stores along n
#pragma unroll
        for (int i = 0; i < 4; ++i) {
            int mm0 = m0 + wr * 64 + i * 16 + lhi * 4;
            int b_ = mm0 >> 10, nn0 = mm0 & 1023;
#pragma unroll
            for (int j = 0; j < 4; ++j) {
                int d = j * 16 + l15;
                s16x4 v;
#pragma unroll
                for (int r = 0; r < 4; ++r) v[r] = (short)f2bf(acc[i][j][r]);
                *(s16x4*)(vto + (((size_t)(b_ * NHEADS + h) * HDIM + d) << 10) + nn0) = v;
            }
        }
    }
}

__global__ __launch_bounds__(256)
void gemm_proj_mfma(const unsigned short* __restrict__ A,
                    const unsigned short* __restrict__ W,
                    const float* __restrict__ pb, float* __restrict__ out)
{
    __shared__ unsigned short Al[2][128][64];
    __shared__ unsigned short Bl[2][128][64];

    // bijective XCD swizzle: 384 = 8 x 48
    const int b0 = blockIdx.x;
    const int sw = (b0 & 7) * 48 + (b0 >> 3);
    const int bx = sw % 6, by = sw / 6;
    const int m0 = by * 128;
    const int n0 = bx * 128;
    const int lane = threadIdx.x & 63, w = threadIdx.x >> 6;
    const int wr = w >> 1, wc = w & 1;
    const int l15 = lane & 15, lhi = lane >> 4;

    const int srow8 = lane >> 3;
    const int sch8  = (lane & 7) ^ srow8;

    f32x4 acc[4][4];
#pragma unroll
    for (int i = 0; i < 4; ++i)
#pragma unroll
        for (int j = 0; j < 4; ++j)
            acc[i][j] = (f32x4){0.f, 0.f, 0.f, 0.f};

    const char* Ab = (const char*)A;
    const char* Wb = (const char*)W;

    STG_HALF(0, 0, 0)
    STG_HALF(0, 0, 1)

    for (int kt = 0; kt < 12; ++kt) {
        const int cur = kt & 1;
        if (kt + 1 < 12) {
            STG_HALF(cur ^ 1, kt + 1, 0)
            asm volatile("s_waitcnt vmcnt(4)" ::: "memory");
        } else {
            asm volatile("s_waitcnt vmcnt(0)" ::: "memory");
        }
        __builtin_amdgcn_s_barrier();

        {
            s16x8 ar[4], br[4];
            PHASE_READS(cur, 0, ar, br)
            if (kt + 1 < 12) { STG_HALF(cur ^ 1, kt + 1, 1) }
            __builtin_amdgcn_s_setprio(1);
            MFMA_SWAP(ar, br)
            __builtin_amdgcn_s_setprio(0);
        }
        __builtin_amdgcn_s_barrier();

        {
            s16x8 ar[4], br[4];
            PHASE_READS(cur, 1, ar, br)
            __builtin_amdgcn_s_setprio(1);
            MFMA_SWAP(ar, br)
            __builtin_amdgcn_s_setprio(0);
        }
        __builtin_amdgcn_s_barrier();
    }

    float4 bias[4];
#pragma unroll
    for (int j = 0; j < 4; ++j)
        bias[j] = *(const float4*)&pb[n0 + wc * 64 + j * 16 + lhi * 4];
#pragma unroll
    for (int i = 0; i < 4; ++i) {
        int mm = m0 + wr * 64 + i * 16 + l15;
        float* rowp = out + (size_t)mm * C_DIM + n0 + wc * 64;
#pragma unroll
        for (int j = 0; j < 4; ++j) {
            float4 o = {acc[i][j][0] + bias[j].x, acc[i][j][1] + bias[j].y,
                        acc[i][j][2] + bias[j].z, acc[i][j][3] + bias[j].w};
            *(float4*)(rowp + j * 16 + lhi * 4) = o;
        }
    }
}

// ============ MFMA flash attention: 8 waves, 256 q-rows/block ============
// Softmax in exp2 domain: SCALE2 = 0.125*log2e, bias table pre-scaled by
// log2e -> every exp is a bare v_exp_f32 (saves the per-exp v_mul).
__global__ __launch_bounds__(512)
void attn_mfma_kernel(const unsigned short* __restrict__ qb,
                      const unsigned short* __restrict__ kb,
                      const unsigned short* __restrict__ vtb,
                      const float* __restrict__ btab,
                      unsigned short* __restrict__ out)
{
    __shared__ unsigned short Klds[2][64][64];     // 16 KB
    __shared__ unsigned short Vlds[2][64][64];     // 16 KB
    __shared__ unsigned short Plds[8][2][16][72];  // 36 KB
    __shared__ float bt[BTSL2];                    // 9.8 KB

    // XCD-local decode: 384 = 8 xcd x 48; all 4 q-blocks of one (b,h)
    // on one XCD; 12 heads/XCD -> K/V working set 3 MB < 4 MB L2.
    const int d0 = blockIdx.x;
    const int xcd = d0 & 7;
    const int idx = d0 >> 3;               // 0..47
    const int qblk = idx & 3;
    const int hb = (idx >> 2) * 8 + xcd;   // 0..95
    const int h = hb % NHEADS, b = hb / NHEADS;

    const int n0 = qblk * 256;
    const int t = threadIdx.x;
    const int lane = t & 63, w = t >> 6;   // w 0..7
    const int l15 = lane & 15, lhi = lane >> 4;

    const size_t headND = ((size_t)(b * NHEADS + h)) * SEQ * HDIM;
    const char* qg = (const char*)(qb + headND);
    const char* kg = (const char*)(kb + headND);
    const char* vg = (const char*)(vtb + headND);   // [64][1024] bf16

    // Q fragments, 2 groups (rows n0 + w*32 + g*16 + l15)
    s16x8 qf[2][2];
#pragma unroll
    for (int g = 0; g < 2; ++g) {
        const char* qrow = qg + (size_t)(n0 + w * 32 + g * 16 + l15) * 128;
        qf[g][0] = *(const s16x8*)(qrow + lhi * 16);
        qf[g][1] = *(const s16x8*)(qrow + 64 + lhi * 16);
    }
    {
        const int btbase = h * TBL + (n0 >> 5) * 63;
        for (int i = t; i < BTSL2; i += 512) bt[i] = btab[btbase + i];
    }

    // compressed bias indices (r=0); bidx[n][r] = bidx0[n] - r
    int bidx0[4];
#pragma unroll
    for (int n = 0; n < 4; ++n) {
        int koff = n * 16 + lhi * 4;
        int dyl = w - (koff >> 5) + 31;
        int dx = l15 - (koff & 31) + 31;
        bidx0[n] = dyl * 63 + dx;
    }

    f32x4 of[2][4];
    float m_i[2] = {-1e30f, -1e30f}, l_i[2] = {0.f, 0.f};
#pragma unroll
    for (int g = 0; g < 2; ++g)
#pragma unroll
        for (int n = 0; n < 4; ++n) of[g][n] = (f32x4){0.f, 0.f, 0.f, 0.f};

    const int krow = w * 8 + (lane >> 3);   // staged K/V row
    const int chk  = (lane & 7) ^ (krow & 7);

    asm volatile("s_waitcnt vmcnt(0)" ::: "memory");   // drain pre-loop vmem
    GLOAD_LDS16(kg + (size_t)krow * 128 + chk * 16, &Klds[0][w * 8][0]);
    GLOAD_LDS16(vg + (size_t)krow * 2048 + chk * 16, &Vlds[0][w * 8][0]);
    asm volatile("s_waitcnt lgkmcnt(0)" ::: "memory");   // bt ds_writes visible
    __builtin_amdgcn_s_barrier();

    int boff = 0;                        // bias slice offset: -126 per tile
    for (int kt = 0; kt < 16; ++kt) {
        const int cur = kt & 1;
        if (kt + 1 < 16) {
            const int c1 = (kt + 1) * 64;
            GLOAD_LDS16(kg + (size_t)(c1 + krow) * 128 + chk * 16,
                        &Klds[cur ^ 1][w * 8][0]);
            GLOAD_LDS16(vg + (size_t)krow * 2048 + c1 * 2 + chk * 16,
                        &Vlds[cur ^ 1][w * 8][0]);
            asm volatile("s_waitcnt vmcnt(2)" ::: "memory");   // oldest 2 = this tile
        } else {
            asm volatile("s_waitcnt vmcnt(0)" ::: "memory");
        }
        __builtin_amdgcn_s_barrier();

        // ---- S^T = K Q, both groups (K fragments shared) ----
        f32x4 sf[2][4];
#pragma unroll
        for (int n = 0; n < 4; ++n) {
            int key = 16 * n + l15;
            const char* krp = (const char*)&Klds[cur][key][0];
            s16x8 kf0 = *(const s16x8*)(krp + ((lhi     ^ (key & 7)) * 16));
            s16x8 kf1 = *(const s16x8*)(krp + (((4+lhi) ^ (key & 7)) * 16));
            f32x4 z = (f32x4){0.f, 0.f, 0.f, 0.f};
            sf[0][n] = __builtin_amdgcn_mfma_f32_16x16x32_bf16(kf0, qf[0][0], z, 0, 0, 0);
            sf[0][n] = __builtin_amdgcn_mfma_f32_16x16x32_bf16(kf1, qf[0][1], sf[0][n], 0, 0, 0);
            sf[1][n] = __builtin_amdgcn_mfma_f32_16x16x32_bf16(kf0, qf[1][0], z, 0, 0, 0);
            sf[1][n] = __builtin_amdgcn_mfma_f32_16x16x32_bf16(kf1, qf[1][1], sf[1][n], 0, 0, 0);
        }

        // ---- per-group lane-local softmax (exp2 domain) ----
#pragma unroll
        for (int g = 0; g < 2; ++g) {
            const int gb = g * 16;
            float s_[4][4];
            float mx = -1e30f;
#pragma unroll
            for (int n = 0; n < 4; ++n)
#pragma unroll
                for (int r = 0; r < 4; ++r) {
                    s_[n][r] = fmaf(sf[g][n][r], SCALE2,
                                    bt[bidx0[n] - r + gb + boff]);
                    mx = fmaxf(mx, s_[n][r]);
                }
            mx = fmaxf(mx, __shfl_xor(mx, 16));
            mx = fmaxf(mx, __shfl_xor(mx, 32));
            if (__any(mx > m_i[g] + DEFER_THR)) {    // defer-max (T13)
                float mn = fmaxf(m_i[g], mx);
                float sc = exp2f(m_i[g] - mn);
                m_i[g] = mn;
                l_i[g] *= sc;
#pragma unroll
                for (int r = 0; r < 4; ++r) {
                    float scr = __shfl(sc, lhi * 4 + r);
#pragma unroll
                    for (int n = 0; n < 4; ++n) of[g][n][r] *= scr;
                }
            }
            float rs = 0.f;
#pragma unroll
            for (int n = 0; n < 4; ++n) {
                float p0 = exp2f(s_[n][0] - m_i[g]);
                float p1 = exp2f(s_[n][1] - m_i[g]);
                float p2 = exp2f(s_[n][2] - m_i[g]);
                float p3 = exp2f(s_[n][3] - m_i[g]);
                rs += (p0 + p1) + (p2 + p3);
                u32x2 pw;
                pw[0] = cvtpk(p0, p1);
                pw[1] = cvtpk(p2, p3);
                *(u32x2*)&Plds[w][g][l15][n * 16 + lhi * 4] = pw;
            }
            rs += __shfl_xor(rs, 16);
            rs += __shfl_xor(rs, 32);
            l_i[g] += rs;
        }
        boff -= 126;
        // (no explicit lgkm drain: Plds deps are compiler-visible, per-wave)

        // ---- O += P V, both groups (V fragments shared) ----
#pragma unroll
        for (int kwin = 0; kwin < 2; ++kwin) {
            s16x8 pa0 = *(const s16x8*)&Plds[w][0][l15][kwin * 32 + lhi * 8];
            s16x8 pa1 = *(const s16x8*)&Plds[w][1][l15][kwin * 32 + lhi * 8];
#pragma unroll
            for (int n = 0; n < 4; ++n) {
                int d  = 16 * n + l15;
                int cd = kwin * 4 + lhi;
                const char* vrow = (const char*)&Vlds[cur][d][0];
                s16x8 vf = *(const s16x8*)(vrow + ((cd ^ (d & 7)) * 16));
                of[0][n] = __builtin_amdgcn_mfma_f32_16x16x32_bf16(pa0, vf, of[0][n], 0, 0, 0);
                of[1][n] = __builtin_amdgcn_mfma_f32_16x16x32_bf16(pa1, vf, of[1][n], 0, 0, 0);
            }
        }
        asm volatile("s_waitcnt lgkmcnt(0)" ::: "memory");   // buf[cur] reads done
        __builtin_amdgcn_s_barrier();
    }

    // ---- epilogue per group ----
#pragma unroll
    for (int g = 0; g < 2; ++g) {
        float inv = 1.f / l_i[g];
#pragma unroll
        for (int r = 0; r < 4; ++r) {
            float invr = __shfl(inv, lhi * 4 + r);
            int nq = n0 + w * 32 + g * 16 + lhi * 4 + r;
            unsigned short* orow = out + ((size_t)b * SEQ + nq) * C_DIM + h * 64;
#pragma unroll
            for (int n = 0; n < 4; ++n)
                orow[16 * n + l15] = f2bf(of[g][n][r] * invr);
        }
    }
}

extern "C" void kernel_launch(void* const* d_in, const int* in_sizes, int n_in,
                              void* d_out, int out_size, void* d_ws, size_t ws_size,
                              hipStream_t stream) {
    const float* x      = (const float*)d_in[0];
    const float* qkv_w  = (const float*)d_in[1];
    const float* proj_w = (const float*)d_in[2];
    const float* proj_b = (const float*)d_in[3];
    const float* rpb_w1 = (const float*)d_in[4];
    const float* rpb_b1 = (const float*)d_in[5];
    const float* rpb_w2 = (const float*)d_in[6];
    const float* rpb_b2 = (const float*)d_in[7];
    float* out = (float*)d_out;

    char* wsb = (char*)d_ws;
    unsigned short* qbuf    = (unsigned short*)(wsb);
    unsigned short* kbuf    = (unsigned short*)(wsb + 12582912);
    unsigned short* vtbuf   = (unsigned short*)(wsb + 25165824);
    unsigned short* abuf    = (unsigned short*)(wsb + 37748736);
    float*          btab    = (float*)         (wsb + 50331648);
    unsigned short* xbf     = (unsigned short*)(wsb + 50522160);
    unsigned short* qkvwbf  = (unsigned short*)(wsb + 63105072);
    unsigned short* projwbf = (unsigned short*)(wsb + 66644016);

    // merged prep: casts + rpb table (one launch)
    prep_kernel<<<dim3(CVTB + (TBL + 255) / 256), dim3(256), 0, stream>>>(
        x, xbf, qkv_w, qkvwbf, proj_w, projwbf,
        rpb_w1, rpb_b1, rpb_w2, rpb_b2, btab);

    // QKV GEMM: [8192,768] @ [2304,768]^T (128x128, BK=64, 2 blocks/CU)
    gemm_qkv_mfma<<<dim3(1152), dim3(256), 0, stream>>>(
        xbf, qkvwbf, qbuf, kbuf, vtbuf);

    // attention: 384 blocks (8 XCD x 48), 512 threads
    attn_mfma_kernel<<<dim3(384), dim3(512), 0, stream>>>(
        qbuf, kbuf, vtbuf, btab, abuf);

    // proj GEMM: [8192,768] @ [768,768]^T + bias (128x128, BK=64, 2 blocks/CU)
    gemm_proj_mfma<<<dim3(384), dim3(256), 0, stream>>>(
        abuf, projwbf, proj_b, out);
}

// Round 23
// 151.971 us; speedup vs baseline: 1.0805x; 1.0805x over previous
//
#include <hip/hip_runtime.h>

#define C_DIM 768
#define NHEADS 12
#define HDIM 64
#define BATCH 8
#define SEQ 1024
#define SCALE_F 0.125f          // 64^-0.5
#define TBL 3969                // 63*63 per head
#define BTSL2 2457              // 39*63 per-block bias slice (256 q-rows)

typedef float f32x4 __attribute__((ext_vector_type(4)));
typedef short s16x4 __attribute__((ext_vector_type(4)));
typedef short s16x8 __attribute__((ext_vector_type(8)));
typedef unsigned int u32x2 __attribute__((ext_vector_type(2)));

// single-op bf16 convert (RNE) — no builtin on gfx950
__device__ inline unsigned short f2bf(float f) {
    unsigned r;
    asm("v_cvt_pk_bf16_f32 %0, %1, %2" : "=v"(r) : "v"(f), "v"(f));
    return (unsigned short)r;
}
// packed pair: low16 = bf16(lo), high16 = bf16(hi)
__device__ inline unsigned cvtpk(float lo, float hi) {
    unsigned r;
    asm("v_cvt_pk_bf16_f32 %0, %1, %2" : "=v"(r) : "v"(lo), "v"(hi));
    return r;
}

#define GLOAD_LDS16(gsrc, ldst)                                                   \
    __builtin_amdgcn_global_load_lds(                                             \
        (const __attribute__((address_space(1))) unsigned int*)(gsrc),            \
        (__attribute__((address_space(3))) unsigned int*)(ldst), 16, 0, 0)

// ---------------- ws layout (bytes) ----------------
// q_bf    [B][H][N][D] bf16   off 0          12582912
// k_bf    [B][H][N][D] bf16   off 12582912   12582912
// vT_bf   [B][H][D][N] bf16   off 25165824   12582912
// abuf    [B][N][C]    bf16   off 37748736   12582912
// btab    [H][63][63]  f32    off 50331648   190512
// x_bf    [8192][768]  bf16   off 50522160   12582912
// qkvw_bf [2304][768]  bf16   off 63105072   3538944
// projw_bf[768][768]   bf16   off 66644016   1179648

// ===== merged prep kernel: f32->bf16 casts (x|qkv_w|proj_w) + rpb table =====
// NOTE round-22 lesson: exp2f() is libm (denorm handling, ~6 ops) — NOT the
// native v_exp_f32. __expf (v_mul+v_exp, 2 ops) is faster; e-domain restored.
#define XU   786432            // x units (8 f32 each)
#define QWU  221184            // qkv_w units
#define PWU  73728             // proj_w units
#define CVTB 4224              // cast blocks: (XU+QWU+PWU)/256
__global__ __launch_bounds__(256)
void prep_kernel(const float* __restrict__ x, unsigned short* __restrict__ xo,
                 const float* __restrict__ qw, unsigned short* __restrict__ qwo,
                 const float* __restrict__ pw, unsigned short* __restrict__ pwo,
                 const float* __restrict__ w1, const float* __restrict__ b1,
                 const float* __restrict__ w2, const float* __restrict__ b2,
                 float* __restrict__ btab)
{
    if (blockIdx.x >= CVTB) {   // rpb table portion
        int t = (blockIdx.x - CVTB) * 256 + threadIdx.x;
        if (t >= TBL) return;
        float dy = (float)(t / 63 - 31);
        float dx = (float)(t % 63 - 31);
        float acc[NHEADS];
#pragma unroll
        for (int h = 0; h < NHEADS; ++h) acc[h] = b2[h];
        for (int j = 0; j < 64; ++j) {
            float hj = fmaf(w1[j * 2], dx, fmaf(w1[j * 2 + 1], dy, b1[j]));
            hj = fmaxf(hj, 0.f);
#pragma unroll
            for (int h = 0; h < NHEADS; ++h) acc[h] = fmaf(w2[h * 64 + j], hj, acc[h]);
        }
#pragma unroll
        for (int h = 0; h < NHEADS; ++h) btab[h * TBL + t] = acc[h];
        return;
    }
    int i = blockIdx.x * 256 + threadIdx.x;
    const float* in; unsigned short* out;
    if (i < XU)                  { in = x;  out = xo; }
    else if (i < XU + QWU)       { in = qw; out = qwo; i -= XU; }
    else                         { in = pw; out = pwo; i -= XU + QWU; }
    const float4* p = (const float4*)in + (size_t)i * 2;
    float4 a = p[0], b = p[1];
    s16x8 v;
    v[0] = (short)f2bf(a.x); v[1] = (short)f2bf(a.y);
    v[2] = (short)f2bf(a.z); v[3] = (short)f2bf(a.w);
    v[4] = (short)f2bf(b.x); v[5] = (short)f2bf(b.y);
    v[6] = (short)f2bf(b.z); v[7] = (short)f2bf(b.w);
    *((s16x8*)out + i) = v;
}

// ============ Phase-interleaved MFMA GEMM — 128x128, 4 waves, BK=64 ============
// (round-19 configuration: session best across 9 structural variants.)

#define MFMA_SWAP(aa, bb)                                          \
    _Pragma("unroll") for (int i_ = 0; i_ < 4; ++i_)               \
    _Pragma("unroll") for (int j_ = 0; j_ < 4; ++j_)               \
        acc[i_][j_] = __builtin_amdgcn_mfma_f32_16x16x32_bf16(     \
            bb[j_], aa[i_], acc[i_][j_], 0, 0, 0);

#define MFMA_NORM(aa, bb)                                          \
    _Pragma("unroll") for (int i_ = 0; i_ < 4; ++i_)               \
    _Pragma("unroll") for (int j_ = 0; j_ < 4; ++j_)               \
        acc[i_][j_] = __builtin_amdgcn_mfma_f32_16x16x32_bf16(     \
            aa[i_], bb[j_], acc[i_][j_], 0, 0, 0);

// stage half of a K-tile: wave w covers A rows w*32+half*16+{0..15} (2 calls)
// and B rows likewise (2 calls) -> 4 loads per wave per half
#define STG_HALF(buf, kt, half)                                                    \
    GLOAD_LDS16(Ab + ((size_t)(m0 + w * 32 + (half) * 16 + srow8) * 768 +          \
                (kt) * 64) * 2 + sch8 * 16, &Al[buf][w * 32 + (half) * 16][0]);    \
    GLOAD_LDS16(Ab + ((size_t)(m0 + w * 32 + (half) * 16 + 8 + srow8) * 768 +      \
                (kt) * 64) * 2 + sch8 * 16, &Al[buf][w * 32 + (half) * 16 + 8][0]);\
    GLOAD_LDS16(Wb + ((size_t)(n0 + w * 32 + (half) * 16 + srow8) * 768 +          \
                (kt) * 64) * 2 + sch8 * 16, &Bl[buf][w * 32 + (half) * 16][0]);    \
    GLOAD_LDS16(Wb + ((size_t)(n0 + w * 32 + (half) * 16 + 8 + srow8) * 768 +      \
                (kt) * 64) * 2 + sch8 * 16, &Bl[buf][w * 32 + (half) * 16 + 8][0]);

// phase fragment reads: logical chunk s*4+lhi at physical (c ^ (row&7))
#define PHASE_READS(cur, s, ar, br)                                                \
    _Pragma("unroll") for (int i_ = 0; i_ < 4; ++i_) {                             \
        ar[i_] = *(const s16x8*)((const char*)&Al[cur][wr * 64 + i_ * 16 + l15][0] \
                 + ((((s) * 4 + lhi) ^ (l15 & 7)) * 16));                          \
        br[i_] = *(const s16x8*)((const char*)&Bl[cur][wc * 64 + i_ * 16 + l15][0] \
                 + ((((s) * 4 + lhi) ^ (l15 & 7)) * 16));                          \
    }

__global__ __launch_bounds__(256)
void gemm_qkv_mfma(const unsigned short* __restrict__ A,
                   const unsigned short* __restrict__ W,
                   unsigned short* __restrict__ qo, unsigned short* __restrict__ ko,
                   unsigned short* __restrict__ vto)
{
    __shared__ unsigned short Al[2][128][64];   // 32 KB
    __shared__ unsigned short Bl[2][128][64];   // 32 KB

    // bijective XCD swizzle: 1152 = 8 x 144
    const int b0 = blockIdx.x;
    const int sw = (b0 & 7) * 144 + (b0 >> 3);
    const int bx = sw % 18, by = sw / 18;
    const int m0 = by * 128;
    const int n0 = bx * 128;
    const int lane = threadIdx.x & 63, w = threadIdx.x >> 6;   // w 0..3
    const int wr = w >> 1, wc = w & 1;                          // 2m x 2n
    const int l15 = lane & 15, lhi = lane >> 4;

    const int which = n0 / 768;              // 0=q 1=k 2=v (block-uniform)
    const int ncol0 = n0 - which * 768;

    const int srow8 = lane >> 3;             // 0..7 within 8-row group
    const int sch8  = (lane & 7) ^ srow8;    // pre-swizzled global chunk

    f32x4 acc[4][4];
#pragma unroll
    for (int i = 0; i < 4; ++i)
#pragma unroll
        for (int j = 0; j < 4; ++j)
            acc[i][j] = (f32x4){0.f, 0.f, 0.f, 0.f};

    const char* Ab = (const char*)A;
    const char* Wb = (const char*)W;

    STG_HALF(0, 0, 0)
    STG_HALF(0, 0, 1)

    for (int kt = 0; kt < 12; ++kt) {
        const int cur = kt & 1;
        if (kt + 1 < 12) {
            STG_HALF(cur ^ 1, kt + 1, 0)                       // batch1(kt+1)
            asm volatile("s_waitcnt vmcnt(4)" ::: "memory");   // tile kt landed
        } else {
            asm volatile("s_waitcnt vmcnt(0)" ::: "memory");
        }
        __builtin_amdgcn_s_barrier();

        {   // phase 1: k-lo (compiler fine-schedules ds_read -> MFMA)
            s16x8 ar[4], br[4];
            PHASE_READS(cur, 0, ar, br)
            if (kt + 1 < 12) { STG_HALF(cur ^ 1, kt + 1, 1) }  // batch2(kt+1)
            __builtin_amdgcn_s_setprio(1);
            if (which < 2) { MFMA_SWAP(ar, br) } else { MFMA_NORM(ar, br) }
            __builtin_amdgcn_s_setprio(0);
        }
        __builtin_amdgcn_s_barrier();

        {   // phase 2: k-hi
            s16x8 ar[4], br[4];
            PHASE_READS(cur, 1, ar, br)
            __builtin_amdgcn_s_setprio(1);
            if (which < 2) { MFMA_SWAP(ar, br) } else { MFMA_NORM(ar, br) }
            __builtin_amdgcn_s_setprio(0);
        }
        __builtin_amdgcn_s_barrier();   // all reads of buf[cur] done -> reusable
    }

    const int h = (ncol0 >> 6) + wc;         // 64-col wave block = one head's d-range
    if (which < 2) {
        // swapped: D[n][m], m on l15 axis -> contiguous d-stores
        unsigned short* dst0 = (which == 0) ? qo : ko;
#pragma unroll
        for (int i = 0; i < 4; ++i) {
            int mm = m0 + wr * 64 + i * 16 + l15;
            int b_ = mm >> 10, nn = mm & 1023;
            unsigned short* rowp = dst0 + (((size_t)(b_ * NHEADS + h) * SEQ + nn) << 6);
#pragma unroll
            for (int j = 0; j < 4; ++j) {
                s16x4 v;
#pragma unroll
                for (int r = 0; r < 4; ++r) v[r] = (short)f2bf(acc[i][j][r]);
                *(s16x4*)(rowp + j * 16 + lhi * 4) = v;
            }
        }
    } else {
        // normal: D[m][n]; m contiguous over reg -> vT stores along n
#pragma unroll
        for (int i = 0; i < 4; ++i) {
            int mm0 = m0 + wr * 64 + i * 16 + lhi * 4;
            int b_ = mm0 >> 10, nn0 = mm0 & 1023;
#pragma unroll
            for (int j = 0; j < 4; ++j) {
                int d = j * 16 + l15;
                s16x4 v;
#pragma unroll
                for (int r = 0; r < 4; ++r) v[r] = (short)f2bf(acc[i][j][r]);
                *(s16x4*)(vto + (((size_t)(b_ * NHEADS + h) * HDIM + d) << 10) + nn0) = v;
            }
        }
    }
}

__global__ __launch_bounds__(256)
void gemm_proj_mfma(const unsigned short* __restrict__ A,
                    const unsigned short* __restrict__ W,
                    const float* __restrict__ pb, float* __restrict__ out)
{
    __shared__ unsigned short Al[2][128][64];
    __shared__ unsigned short Bl[2][128][64];

    // bijective XCD swizzle: 384 = 8 x 48
    const int b0 = blockIdx.x;
    const int sw = (b0 & 7) * 48 + (b0 >> 3);
    const int bx = sw % 6, by = sw / 6;
    const int m0 = by * 128;
    const int n0 = bx * 128;
    const int lane = threadIdx.x & 63, w = threadIdx.x >> 6;
    const int wr = w >> 1, wc = w & 1;
    const int l15 = lane & 15, lhi = lane >> 4;

    const int srow8 = lane >> 3;
    const int sch8  = (lane & 7) ^ srow8;

    f32x4 acc[4][4];
#pragma unroll
    for (int i = 0; i < 4; ++i)
#pragma unroll
        for (int j = 0; j < 4; ++j)
            acc[i][j] = (f32x4){0.f, 0.f, 0.f, 0.f};

    const char* Ab = (const char*)A;
    const char* Wb = (const char*)W;

    STG_HALF(0, 0, 0)
    STG_HALF(0, 0, 1)

    for (int kt = 0; kt < 12; ++kt) {
        const int cur = kt & 1;
        if (kt + 1 < 12) {
            STG_HALF(cur ^ 1, kt + 1, 0)
            asm volatile("s_waitcnt vmcnt(4)" ::: "memory");
        } else {
            asm volatile("s_waitcnt vmcnt(0)" ::: "memory");
        }
        __builtin_amdgcn_s_barrier();

        {
            s16x8 ar[4], br[4];
            PHASE_READS(cur, 0, ar, br)
            if (kt + 1 < 12) { STG_HALF(cur ^ 1, kt + 1, 1) }
            __builtin_amdgcn_s_setprio(1);
            MFMA_SWAP(ar, br)
            __builtin_amdgcn_s_setprio(0);
        }
        __builtin_amdgcn_s_barrier();

        {
            s16x8 ar[4], br[4];
            PHASE_READS(cur, 1, ar, br)
            __builtin_amdgcn_s_setprio(1);
            MFMA_SWAP(ar, br)
            __builtin_amdgcn_s_setprio(0);
        }
        __builtin_amdgcn_s_barrier();
    }

    float4 bias[4];
#pragma unroll
    for (int j = 0; j < 4; ++j)
        bias[j] = *(const float4*)&pb[n0 + wc * 64 + j * 16 + lhi * 4];
#pragma unroll
    for (int i = 0; i < 4; ++i) {
        int mm = m0 + wr * 64 + i * 16 + l15;
        float* rowp = out + (size_t)mm * C_DIM + n0 + wc * 64;
#pragma unroll
        for (int j = 0; j < 4; ++j) {
            float4 o = {acc[i][j][0] + bias[j].x, acc[i][j][1] + bias[j].y,
                        acc[i][j][2] + bias[j].z, acc[i][j][3] + bias[j].w};
            *(float4*)(rowp + j * 16 + lhi * 4) = o;
        }
    }
}

// ============ MFMA flash attention: 8 waves, 256 q-rows/block ============
// (round-21 softmax restored: native __expf, e-domain)
__global__ __launch_bounds__(512)
void attn_mfma_kernel(const unsigned short* __restrict__ qb,
                      const unsigned short* __restrict__ kb,
                      const unsigned short* __restrict__ vtb,
                      const float* __restrict__ btab,
                      unsigned short* __restrict__ out)
{
    __shared__ unsigned short Klds[2][64][64];     // 16 KB
    __shared__ unsigned short Vlds[2][64][64];     // 16 KB
    __shared__ unsigned short Plds[8][2][16][72];  // 36 KB
    __shared__ float bt[BTSL2];                    // 9.8 KB

    // XCD-local decode: 384 = 8 xcd x 48; all 4 q-blocks of one (b,h)
    // on one XCD; 12 heads/XCD -> K/V working set 3 MB < 4 MB L2.
    const int d0 = blockIdx.x;
    const int xcd = d0 & 7;
    const int idx = d0 >> 3;               // 0..47
    const int qblk = idx & 3;
    const int hb = (idx >> 2) * 8 + xcd;   // 0..95
    const int h = hb % NHEADS, b = hb / NHEADS;

    const int n0 = qblk * 256;
    const int t = threadIdx.x;
    const int lane = t & 63, w = t >> 6;   // w 0..7
    const int l15 = lane & 15, lhi = lane >> 4;

    const size_t headND = ((size_t)(b * NHEADS + h)) * SEQ * HDIM;
    const char* qg = (const char*)(qb + headND);
    const char* kg = (const char*)(kb + headND);
    const char* vg = (const char*)(vtb + headND);   // [64][1024] bf16

    // Q fragments, 2 groups (rows n0 + w*32 + g*16 + l15)
    s16x8 qf[2][2];
#pragma unroll
    for (int g = 0; g < 2; ++g) {
        const char* qrow = qg + (size_t)(n0 + w * 32 + g * 16 + l15) * 128;
        qf[g][0] = *(const s16x8*)(qrow + lhi * 16);
        qf[g][1] = *(const s16x8*)(qrow + 64 + lhi * 16);
    }
    {
        const int btbase = h * TBL + (n0 >> 5) * 63;
        for (int i = t; i < BTSL2; i += 512) bt[i] = btab[btbase + i];
    }

    // compressed bias indices (r=0); bidx[n][r] = bidx0[n] - r
    int bidx0[4];
#pragma unroll
    for (int n = 0; n < 4; ++n) {
        int koff = n * 16 + lhi * 4;
        int dyl = w - (koff >> 5) + 31;
        int dx = l15 - (koff & 31) + 31;
        bidx0[n] = dyl * 63 + dx;
    }

    f32x4 of[2][4];
    float m_i[2] = {-1e30f, -1e30f}, l_i[2] = {0.f, 0.f};
#pragma unroll
    for (int g = 0; g < 2; ++g)
#pragma unroll
        for (int n = 0; n < 4; ++n) of[g][n] = (f32x4){0.f, 0.f, 0.f, 0.f};

    const int krow = w * 8 + (lane >> 3);   // staged K/V row
    const int chk  = (lane & 7) ^ (krow & 7);

    asm volatile("s_waitcnt vmcnt(0)" ::: "memory");   // drain pre-loop vmem
    GLOAD_LDS16(kg + (size_t)krow * 128 + chk * 16, &Klds[0][w * 8][0]);
    GLOAD_LDS16(vg + (size_t)krow * 2048 + chk * 16, &Vlds[0][w * 8][0]);
    asm volatile("s_waitcnt lgkmcnt(0)" ::: "memory");   // bt ds_writes visible
    __builtin_amdgcn_s_barrier();

    int boff = 0;                        // bias slice offset: -126 per tile
    for (int kt = 0; kt < 16; ++kt) {
        const int cur = kt & 1;
        if (kt + 1 < 16) {
            const int c1 = (kt + 1) * 64;
            GLOAD_LDS16(kg + (size_t)(c1 + krow) * 128 + chk * 16,
                        &Klds[cur ^ 1][w * 8][0]);
            GLOAD_LDS16(vg + (size_t)krow * 2048 + c1 * 2 + chk * 16,
                        &Vlds[cur ^ 1][w * 8][0]);
            asm volatile("s_waitcnt vmcnt(2)" ::: "memory");   // oldest 2 = this tile
        } else {
            asm volatile("s_waitcnt vmcnt(0)" ::: "memory");
        }
        __builtin_amdgcn_s_barrier();

        // ---- S^T = K Q, both groups (K fragments shared) ----
        f32x4 sf[2][4];
#pragma unroll
        for (int n = 0; n < 4; ++n) {
            int key = 16 * n + l15;
            const char* krp = (const char*)&Klds[cur][key][0];
            s16x8 kf0 = *(const s16x8*)(krp + ((lhi     ^ (key & 7)) * 16));
            s16x8 kf1 = *(const s16x8*)(krp + (((4+lhi) ^ (key & 7)) * 16));
            f32x4 z = (f32x4){0.f, 0.f, 0.f, 0.f};
            sf[0][n] = __builtin_amdgcn_mfma_f32_16x16x32_bf16(kf0, qf[0][0], z, 0, 0, 0);
            sf[0][n] = __builtin_amdgcn_mfma_f32_16x16x32_bf16(kf1, qf[0][1], sf[0][n], 0, 0, 0);
            sf[1][n] = __builtin_amdgcn_mfma_f32_16x16x32_bf16(kf0, qf[1][0], z, 0, 0, 0);
            sf[1][n] = __builtin_amdgcn_mfma_f32_16x16x32_bf16(kf1, qf[1][1], sf[1][n], 0, 0, 0);
        }

        // ---- per-group lane-local softmax ----
#pragma unroll
        for (int g = 0; g < 2; ++g) {
            const int gb = g * 16;
            float s_[4][4];
            float mx = -1e30f;
#pragma unroll
            for (int n = 0; n < 4; ++n)
#pragma unroll
                for (int r = 0; r < 4; ++r) {
                    s_[n][r] = fmaf(sf[g][n][r], SCALE_F,
                                    bt[bidx0[n] - r + gb + boff]);
                    mx = fmaxf(mx, s_[n][r]);
                }
            mx = fmaxf(mx, __shfl_xor(mx, 16));
            mx = fmaxf(mx, __shfl_xor(mx, 32));
            if (__any(mx > m_i[g] + 8.f)) {          // defer-max (T13)
                float mn = fmaxf(m_i[g], mx);
                float sc = __expf(m_i[g] - mn);
                m_i[g] = mn;
                l_i[g] *= sc;
#pragma unroll
                for (int r = 0; r < 4; ++r) {
                    float scr = __shfl(sc, lhi * 4 + r);
#pragma unroll
                    for (int n = 0; n < 4; ++n) of[g][n][r] *= scr;
                }
            }
            float rs = 0.f;
#pragma unroll
            for (int n = 0; n < 4; ++n) {
                float p0 = __expf(s_[n][0] - m_i[g]);
                float p1 = __expf(s_[n][1] - m_i[g]);
                float p2 = __expf(s_[n][2] - m_i[g]);
                float p3 = __expf(s_[n][3] - m_i[g]);
                rs += (p0 + p1) + (p2 + p3);
                u32x2 pw;
                pw[0] = cvtpk(p0, p1);
                pw[1] = cvtpk(p2, p3);
                *(u32x2*)&Plds[w][g][l15][n * 16 + lhi * 4] = pw;
            }
            rs += __shfl_xor(rs, 16);
            rs += __shfl_xor(rs, 32);
            l_i[g] += rs;
        }
        boff -= 126;
        // (no explicit lgkm drain: Plds deps are compiler-visible, per-wave)

        // ---- O += P V, both groups (V fragments shared) ----
#pragma unroll
        for (int kwin = 0; kwin < 2; ++kwin) {
            s16x8 pa0 = *(const s16x8*)&Plds[w][0][l15][kwin * 32 + lhi * 8];
            s16x8 pa1 = *(const s16x8*)&Plds[w][1][l15][kwin * 32 + lhi * 8];
#pragma unroll
            for (int n = 0; n < 4; ++n) {
                int d  = 16 * n + l15;
                int cd = kwin * 4 + lhi;
                const char* vrow = (const char*)&Vlds[cur][d][0];
                s16x8 vf = *(const s16x8*)(vrow + ((cd ^ (d & 7)) * 16));
                of[0][n] = __builtin_amdgcn_mfma_f32_16x16x32_bf16(pa0, vf, of[0][n], 0, 0, 0);
                of[1][n] = __builtin_amdgcn_mfma_f32_16x16x32_bf16(pa1, vf, of[1][n], 0, 0, 0);
            }
        }
        asm volatile("s_waitcnt lgkmcnt(0)" ::: "memory");   // buf[cur] reads done
        __builtin_amdgcn_s_barrier();
    }

    // ---- epilogue per group ----
#pragma unroll
    for (int g = 0; g < 2; ++g) {
        float inv = 1.f / l_i[g];
#pragma unroll
        for (int r = 0; r < 4; ++r) {
            float invr = __shfl(inv, lhi * 4 + r);
            int nq = n0 + w * 32 + g * 16 + lhi * 4 + r;
            unsigned short* orow = out + ((size_t)b * SEQ + nq) * C_DIM + h * 64;
#pragma unroll
            for (int n = 0; n < 4; ++n)
                orow[16 * n + l15] = f2bf(of[g][n][r] * invr);
        }
    }
}

extern "C" void kernel_launch(void* const* d_in, const int* in_sizes, int n_in,
                              void* d_out, int out_size, void* d_ws, size_t ws_size,
                              hipStream_t stream) {
    const float* x      = (const float*)d_in[0];
    const float* qkv_w  = (const float*)d_in[1];
    const float* proj_w = (const float*)d_in[2];
    const float* proj_b = (const float*)d_in[3];
    const float* rpb_w1 = (const float*)d_in[4];
    const float* rpb_b1 = (const float*)d_in[5];
    const float* rpb_w2 = (const float*)d_in[6];
    const float* rpb_b2 = (const float*)d_in[7];
    float* out = (float*)d_out;

    char* wsb = (char*)d_ws;
    unsigned short* qbuf    = (unsigned short*)(wsb);
    unsigned short* kbuf    = (unsigned short*)(wsb + 12582912);
    unsigned short* vtbuf   = (unsigned short*)(wsb + 25165824);
    unsigned short* abuf    = (unsigned short*)(wsb + 37748736);
    float*          btab    = (float*)         (wsb + 50331648);
    unsigned short* xbf     = (unsigned short*)(wsb + 50522160);
    unsigned short* qkvwbf  = (unsigned short*)(wsb + 63105072);
    unsigned short* projwbf = (unsigned short*)(wsb + 66644016);

    // merged prep: casts + rpb table (one launch)
    prep_kernel<<<dim3(CVTB + (TBL + 255) / 256), dim3(256), 0, stream>>>(
        x, xbf, qkv_w, qkvwbf, proj_w, projwbf,
        rpb_w1, rpb_b1, rpb_w2, rpb_b2, btab);

    // QKV GEMM: [8192,768] @ [2304,768]^T (128x128, BK=64, 2 blocks/CU)
    gemm_qkv_mfma<<<dim3(1152), dim3(256), 0, stream>>>(
        xbf, qkvwbf, qbuf, kbuf, vtbuf);

    // attention: 384 blocks (8 XCD x 48), 512 threads
    attn_mfma_kernel<<<dim3(384), dim3(512), 0, stream>>>(
        qbuf, kbuf, vtbuf, btab, abuf);

    // proj GEMM: [8192,768] @ [768,768]^T + bias (128x128, BK=64, 2 blocks/CU)
    gemm_proj_mfma<<<dim3(384), dim3(256), 0, stream>>>(
        abuf, projwbf, proj_b, out);
}